// Round 1
// baseline (1070.624 us; speedup 1.0000x reference)
//
#include <hip/hip_runtime.h>
#include <hip/hip_bf16.h>

typedef __attribute__((ext_vector_type(8))) short bf16x8;   // 8 bf16 = 4 VGPR (MFMA A/B frag)
typedef __attribute__((ext_vector_type(4))) float f32x4;    // MFMA C/D frag
typedef __hip_bfloat16 bf16;
typedef unsigned short u16;

#define NB 8
#define NE 256
#define NN 4096   // H*W
#define SD 64     // H == W == 64

__device__ __forceinline__ u16 f2b_bits(float x) {
  bf16 h = __float2bfloat16(x);
  return *reinterpret_cast<u16*>(&h);
}

// ---------------- split f32 -> bf16 hi/lo (elementwise) ----------------
__global__ __launch_bounds__(256) void k_split(const float* __restrict__ x,
                                               u16* __restrict__ hi, u16* __restrict__ lo, int n4) {
  int i = blockIdx.x * 256 + threadIdx.x;
  if (i >= n4) return;
  float4 v = reinterpret_cast<const float4*>(x)[i];
  float f[4] = {v.x, v.y, v.z, v.w};
  u16 hh[4], ll[4];
#pragma unroll
  for (int j = 0; j < 4; ++j) {
    bf16 hb = __float2bfloat16(f[j]);
    float hf = __bfloat162float(hb);
    hh[j] = *reinterpret_cast<u16*>(&hb);
    ll[j] = f2b_bits(f[j] - hf);
  }
  reinterpret_cast<ushort4*>(hi)[i] = make_ushort4(hh[0], hh[1], hh[2], hh[3]);
  reinterpret_cast<ushort4*>(lo)[i] = make_ushort4(ll[0], ll[1], ll[2], ll[3]);
}

// ------- split + transpose conv weights: w[t][ei][eo] -> whT[t][eo][ei] -------
__global__ __launch_bounds__(256) void k_wsplit(const float* __restrict__ w,
                                                u16* __restrict__ whT, u16* __restrict__ wlT) {
  int i = blockIdx.x * 256 + threadIdx.x;   // < 9*256*256 = 589824
  int t = i >> 16;
  int r = i & 65535;
  int ei = r >> 8, eo = r & 255;
  float x = w[i];
  bf16 hb = __float2bfloat16(x);
  float hf = __bfloat162float(hb);
  int o = (t << 16) + (eo << 8) + ei;
  whT[o] = *reinterpret_cast<u16*>(&hb);
  wlT[o] = f2b_bits(x - hf);
}

// ---------------- conv 3x3 as implicit GEMM, split-bf16 (hi/lo) ----------------
// grid = 8 batches * 32 m-tiles (128 pixels = 2 image rows), block = 512 (8 waves 2x4)
__global__ __launch_bounds__(512) void k_conv(const u16* __restrict__ inh, const u16* __restrict__ inl,
                                              const u16* __restrict__ whT, const u16* __restrict__ wlT,
                                              const float* __restrict__ bias,
                                              u16* __restrict__ x1h, u16* __restrict__ x1l) {
  __shared__ u16 Ah[128][72], Al[128][72];   // pixels x ei-chunk (pad 72: 144B rows, 16B-aligned, ~2-way banks)
  __shared__ u16 Bh[256][72], Bl[256][72];   // eo x ei-chunk
  int bid = blockIdx.x;
  int b = bid >> 5, mt = bid & 31;
  int h0 = mt << 1;                           // first image row of this tile
  int tid = threadIdx.x;
  int wid = tid >> 6, lane = tid & 63;
  int wr = wid >> 2, wc = wid & 3;            // 2 x 4 wave grid: each wave 64pix x 64eo
  int r = lane & 15, g = lane >> 4;
  f32x4 acc[4][4];
#pragma unroll
  for (int i = 0; i < 4; ++i)
#pragma unroll
    for (int j = 0; j < 4; ++j) acc[i][j] = (f32x4){0.f, 0.f, 0.f, 0.f};
  const long ibase = (long)b * NN * NE;

#pragma unroll 1
  for (int t = 0; t < 9; ++t) {
    int dy = t / 3 - 1, dx = t % 3 - 1;
#pragma unroll 1
    for (int kc = 0; kc < 4; ++kc) {          // K-chunk of 64 ei
      __syncthreads();
      // stage A (shifted input rows, zero-padded borders)
      for (int c = tid; c < 1024; c += 512) {
        int pix = c >> 3, c8 = c & 7;
        int ww = pix & 63, hh = h0 + (pix >> 6);
        int sh = hh + dy, sw = ww + dx;
        float4 vh = make_float4(0.f, 0.f, 0.f, 0.f), vl = vh;
        if ((unsigned)sh < 64u && (unsigned)sw < 64u) {
          long off = ibase + ((long)sh * 64 + sw) * NE + kc * 64 + c8 * 8;
          vh = *reinterpret_cast<const float4*>(inh + off);
          vl = *reinterpret_cast<const float4*>(inl + off);
        }
        *reinterpret_cast<float4*>(&Ah[pix][c8 * 8]) = vh;
        *reinterpret_cast<float4*>(&Al[pix][c8 * 8]) = vl;
      }
      // stage B (transposed weights: rows = eo, cols = ei chunk)
      for (int c = tid; c < 2048; c += 512) {
        int eo = c >> 3, c8 = c & 7;
        long off = ((long)t << 16) + eo * 256 + kc * 64 + c8 * 8;
        *reinterpret_cast<float4*>(&Bh[eo][c8 * 8]) = *reinterpret_cast<const float4*>(whT + off);
        *reinterpret_cast<float4*>(&Bl[eo][c8 * 8]) = *reinterpret_cast<const float4*>(wlT + off);
      }
      __syncthreads();
#pragma unroll
      for (int ks = 0; ks < 2; ++ks) {        // two 16x16x32 k-steps per 64-chunk
        int c8 = ks * 4 + g;
        bf16x8 ah[4], al[4], bh[4], bl[4];
#pragma unroll
        for (int mi = 0; mi < 4; ++mi) {
          int row = wr * 64 + mi * 16 + r;
          ah[mi] = *reinterpret_cast<const bf16x8*>(&Ah[row][c8 * 8]);
          al[mi] = *reinterpret_cast<const bf16x8*>(&Al[row][c8 * 8]);
        }
#pragma unroll
        for (int ni = 0; ni < 4; ++ni) {
          int col = wc * 64 + ni * 16 + r;
          bh[ni] = *reinterpret_cast<const bf16x8*>(&Bh[col][c8 * 8]);
          bl[ni] = *reinterpret_cast<const bf16x8*>(&Bl[col][c8 * 8]);
        }
#pragma unroll
        for (int mi = 0; mi < 4; ++mi)
#pragma unroll
          for (int ni = 0; ni < 4; ++ni) {
            acc[mi][ni] = __builtin_amdgcn_mfma_f32_16x16x32_bf16(ah[mi], bh[ni], acc[mi][ni], 0, 0, 0);
            acc[mi][ni] = __builtin_amdgcn_mfma_f32_16x16x32_bf16(ah[mi], bl[ni], acc[mi][ni], 0, 0, 0);
            acc[mi][ni] = __builtin_amdgcn_mfma_f32_16x16x32_bf16(al[mi], bh[ni], acc[mi][ni], 0, 0, 0);
          }
      }
    }
  }
  // epilogue: +bias, re-split to hi/lo bf16
#pragma unroll
  for (int mi = 0; mi < 4; ++mi)
#pragma unroll
    for (int ni = 0; ni < 4; ++ni) {
      int eo = wc * 64 + ni * 16 + r;
      float bz = bias[eo];
#pragma unroll
      for (int i = 0; i < 4; ++i) {
        int pix = mt * 128 + wr * 64 + mi * 16 + g * 4 + i;
        float v = acc[mi][ni][i] + bz;
        bf16 hb = __float2bfloat16(v);
        float hf = __bfloat162float(hb);
        long o = ibase + (long)pix * NE + eo;
        x1h[o] = *reinterpret_cast<u16*>(&hb);
        x1l[o] = f2b_bits(v - hf);
      }
    }
}

// ---------------- transpose x1h[b][m][e] -> x1T[b][e][m] ----------------
__global__ __launch_bounds__(256) void k_trans(const u16* __restrict__ x1h, u16* __restrict__ x1T) {
  __shared__ u16 T[64][72];
  int bid = blockIdx.x;
  int b = bid >> 8, rem = bid & 255;
  int mt = rem >> 2, et = rem & 3;
  int tid = threadIdx.x;
  for (int c = tid; c < 512; c += 256) {
    int rr = c >> 3, c8 = c & 7;
    *reinterpret_cast<float4*>(&T[rr][c8 * 8]) =
        *reinterpret_cast<const float4*>(x1h + ((long)b * NN + mt * 64 + rr) * NE + et * 64 + c8 * 8);
  }
  __syncthreads();
  for (int c = tid; c < 512; c += 256) {
    int er = c >> 3, m8 = c & 7;
    union { u16 u[8]; float4 v; } p;
#pragma unroll
    for (int j = 0; j < 8; ++j) p.u[j] = T[m8 * 8 + j][er];
    *reinterpret_cast<float4*>(x1T + ((long)b * NE + et * 64 + er) * NN + mt * 64 + m8 * 8) = p.v;
  }
}

// ---------------- scores = x1 . x1^T (per batch), split-bf16, f32 out ----------------
// grid = 32x32 tiles of 128x128, block 256 (4 waves 2x2)
__global__ __launch_bounds__(256) void k_scores(const u16* __restrict__ x1h, const u16* __restrict__ x1l,
                                                float* __restrict__ sc, int b) {
  __shared__ u16 Ah[128][72], Al[128][72], Bh[128][72], Bl[128][72];
  int tr = blockIdx.x >> 5, tc = blockIdx.x & 31;
  int tid = threadIdx.x, wid = tid >> 6, lane = tid & 63;
  int wr = wid >> 1, wc = wid & 1;
  int r = lane & 15, g = lane >> 4;
  f32x4 acc[4][4];
#pragma unroll
  for (int i = 0; i < 4; ++i)
#pragma unroll
    for (int j = 0; j < 4; ++j) acc[i][j] = (f32x4){0.f, 0.f, 0.f, 0.f};
  const long base = (long)b * NN * NE;
#pragma unroll 1
  for (int kc = 0; kc < 4; ++kc) {
    __syncthreads();
    for (int c = tid; c < 1024; c += 256) {
      int rr = c >> 3, c8 = c & 7;
      long offA = base + (long)(tr * 128 + rr) * NE + kc * 64 + c8 * 8;
      long offB = base + (long)(tc * 128 + rr) * NE + kc * 64 + c8 * 8;
      *reinterpret_cast<float4*>(&Ah[rr][c8 * 8]) = *reinterpret_cast<const float4*>(x1h + offA);
      *reinterpret_cast<float4*>(&Al[rr][c8 * 8]) = *reinterpret_cast<const float4*>(x1l + offA);
      *reinterpret_cast<float4*>(&Bh[rr][c8 * 8]) = *reinterpret_cast<const float4*>(x1h + offB);
      *reinterpret_cast<float4*>(&Bl[rr][c8 * 8]) = *reinterpret_cast<const float4*>(x1l + offB);
    }
    __syncthreads();
#pragma unroll
    for (int ks = 0; ks < 2; ++ks) {
      int c8 = ks * 4 + g;
      bf16x8 ah[4], al[4], bh[4], bl[4];
#pragma unroll
      for (int mi = 0; mi < 4; ++mi) {
        int row = wr * 64 + mi * 16 + r;
        ah[mi] = *reinterpret_cast<const bf16x8*>(&Ah[row][c8 * 8]);
        al[mi] = *reinterpret_cast<const bf16x8*>(&Al[row][c8 * 8]);
      }
#pragma unroll
      for (int ni = 0; ni < 4; ++ni) {
        int col = wc * 64 + ni * 16 + r;
        bh[ni] = *reinterpret_cast<const bf16x8*>(&Bh[col][c8 * 8]);
        bl[ni] = *reinterpret_cast<const bf16x8*>(&Bl[col][c8 * 8]);
      }
#pragma unroll
      for (int mi = 0; mi < 4; ++mi)
#pragma unroll
        for (int ni = 0; ni < 4; ++ni) {
          acc[mi][ni] = __builtin_amdgcn_mfma_f32_16x16x32_bf16(ah[mi], bh[ni], acc[mi][ni], 0, 0, 0);
          acc[mi][ni] = __builtin_amdgcn_mfma_f32_16x16x32_bf16(ah[mi], bl[ni], acc[mi][ni], 0, 0, 0);
          acc[mi][ni] = __builtin_amdgcn_mfma_f32_16x16x32_bf16(al[mi], bh[ni], acc[mi][ni], 0, 0, 0);
        }
    }
  }
#pragma unroll
  for (int mi = 0; mi < 4; ++mi)
#pragma unroll
    for (int ni = 0; ni < 4; ++ni) {
      int col = tc * 128 + wc * 64 + ni * 16 + r;
#pragma unroll
      for (int i = 0; i < 4; ++i) {
        int row = tr * 128 + wr * 64 + mi * 16 + g * 4 + i;
        sc[(long)row * NN + col] = acc[mi][ni][i];
      }
    }
}

// ------- row softmax, f32 scores -> bf16 attn in place (row-packed at row start) -------
__global__ __launch_bounds__(256) void k_softmax(float* __restrict__ sc) {
  long row = blockIdx.x;
  float* srow = sc + row * NN;
  u16* arow = reinterpret_cast<u16*>(sc) + row * (NN * 2);
  int tid = threadIdx.x;
  float rv[16];
#pragma unroll
  for (int k = 0; k < 4; ++k) {
    float4 v = *reinterpret_cast<const float4*>(srow + k * 1024 + tid * 4);
    rv[k * 4 + 0] = v.x; rv[k * 4 + 1] = v.y; rv[k * 4 + 2] = v.z; rv[k * 4 + 3] = v.w;
  }
  float m = -3.0e38f;
#pragma unroll
  for (int j = 0; j < 16; ++j) m = fmaxf(m, rv[j]);
#pragma unroll
  for (int off = 32; off > 0; off >>= 1) m = fmaxf(m, __shfl_xor(m, off));
  __shared__ float red[8];
  int wid = tid >> 6, lane = tid & 63;
  if (lane == 0) red[wid] = m;
  __syncthreads();                       // also orders: all loads above complete before any write below
  m = fmaxf(fmaxf(red[0], red[1]), fmaxf(red[2], red[3]));
  float s = 0.f;
#pragma unroll
  for (int j = 0; j < 16; ++j) { rv[j] = __expf(rv[j] - m); s += rv[j]; }
#pragma unroll
  for (int off = 32; off > 0; off >>= 1) s += __shfl_xor(s, off);
  if (lane == 0) red[4 + wid] = s;
  __syncthreads();
  s = red[4] + red[5] + red[6] + red[7];
  float inv = 1.0f / s;
#pragma unroll
  for (int k = 0; k < 4; ++k) {
    ushort4 o;
    o.x = f2b_bits(rv[k * 4 + 0] * inv);
    o.y = f2b_bits(rv[k * 4 + 1] * inv);
    o.z = f2b_bits(rv[k * 4 + 2] * inv);
    o.w = f2b_bits(rv[k * 4 + 3] * inv);
    *reinterpret_cast<ushort4*>(arow + k * 1024 + tid * 4) = o;
  }
}

// ------- out[n][e] = (attn . x1)/16 * inputs (per batch), plain bf16 MFMA -------
// grid = 64 m-tiles x 4 e-tiles (64x64), block 256 (4 waves 2x2, each 32x32)
__global__ __launch_bounds__(256) void k_pv(const u16* __restrict__ attn, const u16* __restrict__ x1T,
                                            const float* __restrict__ inp, float* __restrict__ out, int b) {
  __shared__ u16 Aa[64][72], Bt[64][72];
  int tr = blockIdx.x >> 2, tc = blockIdx.x & 3;
  int tid = threadIdx.x, wid = tid >> 6, lane = tid & 63;
  int wr = wid >> 1, wc = wid & 1;
  int r = lane & 15, g = lane >> 4;
  f32x4 acc[2][2];
#pragma unroll
  for (int i = 0; i < 2; ++i)
#pragma unroll
    for (int j = 0; j < 2; ++j) acc[i][j] = (f32x4){0.f, 0.f, 0.f, 0.f};
  const long x1Tbase = (long)b * NE * NN;
#pragma unroll 1
  for (int kc = 0; kc < 64; ++kc) {
    __syncthreads();
    for (int c = tid; c < 512; c += 256) {
      int rr = c >> 3, c8 = c & 7;
      *reinterpret_cast<float4*>(&Aa[rr][c8 * 8]) =
          *reinterpret_cast<const float4*>(attn + (long)(tr * 64 + rr) * (NN * 2) + kc * 64 + c8 * 8);
      *reinterpret_cast<float4*>(&Bt[rr][c8 * 8]) =
          *reinterpret_cast<const float4*>(x1T + x1Tbase + (long)(tc * 64 + rr) * NN + kc * 64 + c8 * 8);
    }
    __syncthreads();
#pragma unroll
    for (int ks = 0; ks < 2; ++ks) {
      int c8 = ks * 4 + g;
      bf16x8 av[2], bv[2];
      av[0] = *reinterpret_cast<const bf16x8*>(&Aa[wr * 32 + r][c8 * 8]);
      av[1] = *reinterpret_cast<const bf16x8*>(&Aa[wr * 32 + 16 + r][c8 * 8]);
      bv[0] = *reinterpret_cast<const bf16x8*>(&Bt[wc * 32 + r][c8 * 8]);
      bv[1] = *reinterpret_cast<const bf16x8*>(&Bt[wc * 32 + 16 + r][c8 * 8]);
#pragma unroll
      for (int mi = 0; mi < 2; ++mi)
#pragma unroll
        for (int ni = 0; ni < 2; ++ni)
          acc[mi][ni] = __builtin_amdgcn_mfma_f32_16x16x32_bf16(av[mi], bv[ni], acc[mi][ni], 0, 0, 0);
    }
  }
  const long obase = (long)b * NN * NE;
#pragma unroll
  for (int mi = 0; mi < 2; ++mi)
#pragma unroll
    for (int ni = 0; ni < 2; ++ni) {
      int e = tc * 64 + wc * 32 + ni * 16 + r;
#pragma unroll
      for (int i = 0; i < 4; ++i) {
        int n = tr * 64 + wr * 32 + mi * 16 + g * 4 + i;
        long o = obase + (long)n * NE + e;
        out[o] = acc[mi][ni][i] * 0.0625f * inp[o];
      }
    }
}

// ---------------- host ----------------
// ws layout (bytes):
//   [0, 67108864)      f32 scores buffer (per-batch, reused); during conv phase the
//                      first 35.9MB of it holds in_hi|in_lo|whT|wlT (dead after conv)
//   [67108864, ..)     x1_hi bf16   (16,777,216)
//   [83886080, ..)     x1_lo bf16   (16,777,216)
//   [100663296, ..)    x1T_hi bf16  (16,777,216)
// total need: 117,440,512 B
extern "C" void kernel_launch(void* const* d_in, const int* in_sizes, int n_in,
                              void* d_out, int out_size, void* d_ws, size_t ws_size,
                              hipStream_t stream) {
  const float* inp   = (const float*)d_in[0];
  const float* convw = (const float*)d_in[1];
  const float* convb = (const float*)d_in[2];
  float* out = (float*)d_out;
  char* ws = (char*)d_ws;

  u16* in_hi = (u16*)(ws);
  u16* in_lo = (u16*)(ws + 16777216);
  u16* whT   = (u16*)(ws + 33554432);
  u16* wlT   = (u16*)(ws + 33554432 + 1179648);
  float* scores = (float*)ws;
  u16* x1h = (u16*)(ws + 67108864);
  u16* x1l = (u16*)(ws + 83886080);
  u16* x1T = (u16*)(ws + 100663296);

  k_split<<<8192, 256, 0, stream>>>(inp, in_hi, in_lo, 2097152);
  k_wsplit<<<2304, 256, 0, stream>>>(convw, whT, wlT);
  k_conv<<<256, 512, 0, stream>>>(in_hi, in_lo, whT, wlT, convb, x1h, x1l);
  k_trans<<<2048, 256, 0, stream>>>(x1h, x1T);
  for (int b = 0; b < NB; ++b) {
    k_scores<<<1024, 256, 0, stream>>>(x1h, x1l, scores, b);
    k_softmax<<<4096, 256, 0, stream>>>(scores);
    k_pv<<<256, 256, 0, stream>>>((const u16*)scores, x1T, inp, out, b);
  }
}

// Round 2
// 568.185 us; speedup vs baseline: 1.8843x; 1.8843x over previous
//
#include <hip/hip_runtime.h>
#include <hip/hip_bf16.h>

typedef __attribute__((ext_vector_type(8))) short bf16x8;   // 8 bf16 = 4 VGPR (MFMA A/B frag)
typedef __attribute__((ext_vector_type(4))) float f32x4;    // MFMA C/D frag
typedef __hip_bfloat16 bf16;
typedef unsigned short u16;

#define NB 8
#define NE 256
#define NN 4096   // H*W
#define SD 64     // H == W == 64

__device__ __forceinline__ u16 f2b_bits(float x) {
  bf16 h = __float2bfloat16(x);
  return *reinterpret_cast<u16*>(&h);
}

// ---------------- split f32 -> bf16 hi/lo (elementwise) ----------------
__global__ __launch_bounds__(256) void k_split(const float* __restrict__ x,
                                               u16* __restrict__ hi, u16* __restrict__ lo, int n4) {
  int i = blockIdx.x * 256 + threadIdx.x;
  if (i >= n4) return;
  float4 v = reinterpret_cast<const float4*>(x)[i];
  float f[4] = {v.x, v.y, v.z, v.w};
  u16 hh[4], ll[4];
#pragma unroll
  for (int j = 0; j < 4; ++j) {
    bf16 hb = __float2bfloat16(f[j]);
    float hf = __bfloat162float(hb);
    hh[j] = *reinterpret_cast<u16*>(&hb);
    ll[j] = f2b_bits(f[j] - hf);
  }
  reinterpret_cast<ushort4*>(hi)[i] = make_ushort4(hh[0], hh[1], hh[2], hh[3]);
  reinterpret_cast<ushort4*>(lo)[i] = make_ushort4(ll[0], ll[1], ll[2], ll[3]);
}

// ------- split + transpose conv weights: w[t][ei][eo] -> whT[t][eo][ei] -------
__global__ __launch_bounds__(256) void k_wsplit(const float* __restrict__ w,
                                                u16* __restrict__ whT, u16* __restrict__ wlT) {
  int i = blockIdx.x * 256 + threadIdx.x;   // < 9*256*256 = 589824
  int t = i >> 16;
  int r = i & 65535;
  int ei = r >> 8, eo = r & 255;
  float x = w[i];
  bf16 hb = __float2bfloat16(x);
  float hf = __bfloat162float(hb);
  int o = (t << 16) + (eo << 8) + ei;
  whT[o] = *reinterpret_cast<u16*>(&hb);
  wlT[o] = f2b_bits(x - hf);
}

// ---------------- conv 3x3 as implicit GEMM, split-bf16 (hi/lo) ----------------
// grid = 8 b * 32 mt * 2 et; block = 256 (4 waves 2x2, each 64pix x 64eo)
// LDS 72KB -> 2 blocks/CU for barrier-stall overlap.
__global__ __launch_bounds__(256) void k_conv(const u16* __restrict__ inh, const u16* __restrict__ inl,
                                              const u16* __restrict__ whT, const u16* __restrict__ wlT,
                                              const float* __restrict__ bias,
                                              u16* __restrict__ x1h, u16* __restrict__ x1l) {
  __shared__ u16 Ah[128][72], Al[128][72];   // pixels x ei-chunk (pad +8 keeps 16B align, ~2-way banks)
  __shared__ u16 Bh[128][72], Bl[128][72];   // eo-tile x ei-chunk
  int b = blockIdx.x >> 6;
  int rem = blockIdx.x & 63;
  int mt = rem >> 1, et = rem & 1;
  int h0 = mt << 1;                           // first image row of this tile
  int tid = threadIdx.x;
  int wid = tid >> 6, lane = tid & 63;
  int wr = wid >> 1, wc = wid & 1;            // 2x2 wave grid: each wave 64pix x 64eo
  int r = lane & 15, g = lane >> 4;
  f32x4 acc[4][4];
#pragma unroll
  for (int i = 0; i < 4; ++i)
#pragma unroll
    for (int j = 0; j < 4; ++j) acc[i][j] = (f32x4){0.f, 0.f, 0.f, 0.f};
  const long ibase = (long)b * NN * NE;

#pragma unroll 1
  for (int t = 0; t < 9; ++t) {
    int dy = t / 3 - 1, dx = t % 3 - 1;
#pragma unroll 1
    for (int kc = 0; kc < 4; ++kc) {          // K-chunk of 64 ei
      __syncthreads();
      // stage A (shifted input rows, zero-padded borders): 128 pix x 64 ei
      for (int c = tid; c < 1024; c += 256) {
        int pix = c >> 3, c8 = c & 7;
        int ww = pix & 63, hh = h0 + (pix >> 6);
        int sh = hh + dy, sw = ww + dx;
        float4 vh = make_float4(0.f, 0.f, 0.f, 0.f), vl = vh;
        if ((unsigned)sh < 64u && (unsigned)sw < 64u) {
          long off = ibase + ((long)sh * 64 + sw) * NE + kc * 64 + c8 * 8;
          vh = *reinterpret_cast<const float4*>(inh + off);
          vl = *reinterpret_cast<const float4*>(inl + off);
        }
        *reinterpret_cast<float4*>(&Ah[pix][c8 * 8]) = vh;
        *reinterpret_cast<float4*>(&Al[pix][c8 * 8]) = vl;
      }
      // stage B (transposed weights: rows = eo within et-tile, cols = ei chunk)
      for (int c = tid; c < 1024; c += 256) {
        int eo = c >> 3, c8 = c & 7;
        long off = ((long)t << 16) + (et * 128 + eo) * 256 + kc * 64 + c8 * 8;
        *reinterpret_cast<float4*>(&Bh[eo][c8 * 8]) = *reinterpret_cast<const float4*>(whT + off);
        *reinterpret_cast<float4*>(&Bl[eo][c8 * 8]) = *reinterpret_cast<const float4*>(wlT + off);
      }
      __syncthreads();
#pragma unroll
      for (int ks = 0; ks < 2; ++ks) {        // two 16x16x32 k-steps per 64-chunk
        int c8 = ks * 4 + g;
        bf16x8 ah[4], al[4], bh[4], bl[4];
#pragma unroll
        for (int mi = 0; mi < 4; ++mi) {
          int row = wr * 64 + mi * 16 + r;
          ah[mi] = *reinterpret_cast<const bf16x8*>(&Ah[row][c8 * 8]);
          al[mi] = *reinterpret_cast<const bf16x8*>(&Al[row][c8 * 8]);
        }
#pragma unroll
        for (int ni = 0; ni < 4; ++ni) {
          int col = wc * 64 + ni * 16 + r;
          bh[ni] = *reinterpret_cast<const bf16x8*>(&Bh[col][c8 * 8]);
          bl[ni] = *reinterpret_cast<const bf16x8*>(&Bl[col][c8 * 8]);
        }
#pragma unroll
        for (int mi = 0; mi < 4; ++mi)
#pragma unroll
          for (int ni = 0; ni < 4; ++ni) {
            acc[mi][ni] = __builtin_amdgcn_mfma_f32_16x16x32_bf16(ah[mi], bh[ni], acc[mi][ni], 0, 0, 0);
            acc[mi][ni] = __builtin_amdgcn_mfma_f32_16x16x32_bf16(ah[mi], bl[ni], acc[mi][ni], 0, 0, 0);
            acc[mi][ni] = __builtin_amdgcn_mfma_f32_16x16x32_bf16(al[mi], bh[ni], acc[mi][ni], 0, 0, 0);
          }
      }
    }
  }
  // epilogue: +bias, re-split to hi/lo bf16
#pragma unroll
  for (int mi = 0; mi < 4; ++mi)
#pragma unroll
    for (int ni = 0; ni < 4; ++ni) {
      int eo = et * 128 + wc * 64 + ni * 16 + r;
      float bz = bias[eo];
#pragma unroll
      for (int i = 0; i < 4; ++i) {
        int pix = mt * 128 + wr * 64 + mi * 16 + g * 4 + i;
        float v = acc[mi][ni][i] + bz;
        bf16 hb = __float2bfloat16(v);
        float hf = __bfloat162float(hb);
        long o = ibase + (long)pix * NE + eo;
        x1h[o] = *reinterpret_cast<u16*>(&hb);
        x1l[o] = f2b_bits(v - hf);
      }
    }
}

// ---------------- transpose x1h[b][m][e] -> x1T[b][e][m] ----------------
__global__ __launch_bounds__(256) void k_trans(const u16* __restrict__ x1h, u16* __restrict__ x1T) {
  __shared__ u16 T[64][72];
  int bid = blockIdx.x;
  int b = bid >> 8, rem = bid & 255;
  int mt = rem >> 2, et = rem & 3;
  int tid = threadIdx.x;
  for (int c = tid; c < 512; c += 256) {
    int rr = c >> 3, c8 = c & 7;
    *reinterpret_cast<float4*>(&T[rr][c8 * 8]) =
        *reinterpret_cast<const float4*>(x1h + ((long)b * NN + mt * 64 + rr) * NE + et * 64 + c8 * 8);
  }
  __syncthreads();
  for (int c = tid; c < 512; c += 256) {
    int er = c >> 3, m8 = c & 7;
    union { u16 u[8]; float4 v; } p;
#pragma unroll
    for (int j = 0; j < 8; ++j) p.u[j] = T[m8 * 8 + j][er];
    *reinterpret_cast<float4*>(x1T + ((long)b * NE + et * 64 + er) * NN + mt * 64 + m8 * 8) = p.v;
  }
}

// ---------------- fused flash attention ----------------
// grid = 8 b * 32 mt (M-tile 128 q-rows), block 512 = 8 waves, wave w owns q-rows [w*16, w*16+16).
// Per KV-tile of 64: stage K hi/lo + Vt; S^T = mfma(K, Q) (q-row = lane&15 -> lane-local
// online softmax, 2 shuffles per reduce); P via per-wave LDS re-fragment; O += P.V.
__global__ __launch_bounds__(512) void k_flash(const u16* __restrict__ x1h, const u16* __restrict__ x1l,
                                               const u16* __restrict__ x1T,
                                               const float* __restrict__ inp, float* __restrict__ out) {
  __shared__ u16 Kh[64][264], Kl[64][264];   // KV-rows x E (pad +8)
  __shared__ u16 Vt[256][72];                // E x KV-rows (pad +8)
  __shared__ u16 Pl[8][16][72];              // per-wave P re-fragment buffer
  int b = blockIdx.x >> 5, mt = blockIdx.x & 31;
  int tid = threadIdx.x, wid = tid >> 6, lane = tid & 63;
  int l15 = lane & 15, g = lane >> 4;

  // Q fragments (hi/lo) in registers: B-operand of S^T = mfma(K, Q):
  // col=lane&15 -> local q-row, k=(lane>>4)*8+j within each 32-k-step.
  const long qrow_g = (long)b * NN + mt * 128 + wid * 16 + l15;
  bf16x8 qh[8], ql[8];
#pragma unroll
  for (int s = 0; s < 8; ++s) {
    qh[s] = *reinterpret_cast<const bf16x8*>(x1h + qrow_g * NE + s * 32 + g * 8);
    ql[s] = *reinterpret_cast<const bf16x8*>(x1l + qrow_g * NE + s * 32 + g * 8);
  }
  f32x4 o[16];
#pragma unroll
  for (int nf = 0; nf < 16; ++nf) o[nf] = (f32x4){0.f, 0.f, 0.f, 0.f};
  float mrow = -1.0e30f, lrow = 0.f;

#pragma unroll 1
  for (int kt = 0; kt < 64; ++kt) {
    // ---- stage K (hi/lo) and Vt ----
    for (int c = tid; c < 2048; c += 512) {
      int row = c >> 5, ch = c & 31;
      long off = ((long)b * NN + kt * 64 + row) * NE + ch * 8;
      *reinterpret_cast<float4*>(&Kh[row][ch * 8]) = *reinterpret_cast<const float4*>(x1h + off);
      *reinterpret_cast<float4*>(&Kl[row][ch * 8]) = *reinterpret_cast<const float4*>(x1l + off);
    }
    for (int c = tid; c < 2048; c += 512) {
      int e = c >> 3, ch = c & 7;
      *reinterpret_cast<float4*>(&Vt[e][ch * 8]) =
          *reinterpret_cast<const float4*>(x1T + ((long)b * NE + e) * NN + kt * 64 + ch * 8);
    }
    __syncthreads();

    // ---- S^T[kcol][qrow] = K . Q, split-bf16 3-term ----
    f32x4 st[4];
#pragma unroll
    for (int mf = 0; mf < 4; ++mf) st[mf] = (f32x4){0.f, 0.f, 0.f, 0.f};
#pragma unroll
    for (int s = 0; s < 8; ++s) {
#pragma unroll
      for (int mf = 0; mf < 4; ++mf) {
        bf16x8 kh = *reinterpret_cast<const bf16x8*>(&Kh[mf * 16 + l15][s * 32 + g * 8]);
        bf16x8 kl = *reinterpret_cast<const bf16x8*>(&Kl[mf * 16 + l15][s * 32 + g * 8]);
        st[mf] = __builtin_amdgcn_mfma_f32_16x16x32_bf16(kh, qh[s], st[mf], 0, 0, 0);
        st[mf] = __builtin_amdgcn_mfma_f32_16x16x32_bf16(kl, qh[s], st[mf], 0, 0, 0);
        st[mf] = __builtin_amdgcn_mfma_f32_16x16x32_bf16(kh, ql[s], st[mf], 0, 0, 0);
      }
    }

    // ---- online softmax (q-row = lane&15; kcol = mf*16 + g*4 + i) ----
    float tmax = -1.0e30f;
#pragma unroll
    for (int mf = 0; mf < 4; ++mf)
#pragma unroll
      for (int i = 0; i < 4; ++i) tmax = fmaxf(tmax, st[mf][i]);
    tmax = fmaxf(tmax, __shfl_xor(tmax, 16));
    tmax = fmaxf(tmax, __shfl_xor(tmax, 32));
    float mnew = fmaxf(mrow, tmax);
    float alpha = __expf(mrow - mnew);
    float psum = 0.f;
#pragma unroll
    for (int mf = 0; mf < 4; ++mf)
#pragma unroll
      for (int i = 0; i < 4; ++i) {
        float p = __expf(st[mf][i] - mnew);
        st[mf][i] = p;
        psum += p;
      }
    psum += __shfl_xor(psum, 16);
    psum += __shfl_xor(psum, 32);
    lrow = lrow * alpha + psum;
    mrow = mnew;

    // ---- write P (bf16) to per-wave LDS: P[qrow][kcol] ----
#pragma unroll
    for (int mf = 0; mf < 4; ++mf) {
      ushort4 pk = make_ushort4(f2b_bits(st[mf][0]), f2b_bits(st[mf][1]),
                                f2b_bits(st[mf][2]), f2b_bits(st[mf][3]));
      *reinterpret_cast<ushort4*>(&Pl[wid][l15][mf * 16 + g * 4]) = pk;
    }

    // ---- rescale O by alpha (O row = g*4 + i; alpha lives at lane (g*4+i)) ----
    float ar[4];
#pragma unroll
    for (int i = 0; i < 4; ++i) ar[i] = __shfl(alpha, g * 4 + i);
#pragma unroll
    for (int nf = 0; nf < 16; ++nf)
#pragma unroll
      for (int i = 0; i < 4; ++i) o[nf][i] *= ar[i];

    // ---- O += P . V ----
#pragma unroll
    for (int s2 = 0; s2 < 2; ++s2) {
      bf16x8 pa = *reinterpret_cast<const bf16x8*>(&Pl[wid][l15][s2 * 32 + g * 8]);
#pragma unroll
      for (int nf = 0; nf < 16; ++nf) {
        bf16x8 bv = *reinterpret_cast<const bf16x8*>(&Vt[nf * 16 + l15][s2 * 32 + g * 8]);
        o[nf] = __builtin_amdgcn_mfma_f32_16x16x32_bf16(pa, bv, o[nf], 0, 0, 0);
      }
    }
    __syncthreads();
  }

  // ---- epilogue: /l /16 * inp ----
  float li[4];
#pragma unroll
  for (int i = 0; i < 4; ++i) li[i] = __shfl(lrow, g * 4 + i);
#pragma unroll
  for (int i = 0; i < 4; ++i) li[i] = 1.0f / (16.0f * li[i]);
  const long obase = (long)b * NN * NE + (mt * 128 + wid * 16) * NE;
#pragma unroll
  for (int nf = 0; nf < 16; ++nf)
#pragma unroll
    for (int i = 0; i < 4; ++i) {
      long off = obase + (long)(g * 4 + i) * NE + nf * 16 + l15;
      out[off] = o[nf][i] * li[i] * inp[off];
    }
}

// ---------------- host ----------------
// ws layout (bytes):
//   [0,        16MB)   x1_hi bf16
//   [16MB,     32MB)   x1_lo bf16
//   [32MB,     48MB)   x1T_hi bf16
//   [48MB,     64MB)   in_hi bf16   (dead after conv)
//   [64MB,     80MB)   in_lo bf16   (dead after conv)
//   [80MB,     +1.13MB) whT, then wlT (dead after conv)
// total need: ~82.4MB
extern "C" void kernel_launch(void* const* d_in, const int* in_sizes, int n_in,
                              void* d_out, int out_size, void* d_ws, size_t ws_size,
                              hipStream_t stream) {
  const float* inp   = (const float*)d_in[0];
  const float* convw = (const float*)d_in[1];
  const float* convb = (const float*)d_in[2];
  float* out = (float*)d_out;
  char* ws = (char*)d_ws;

  u16* x1h   = (u16*)(ws);
  u16* x1l   = (u16*)(ws + 16777216L);
  u16* x1T   = (u16*)(ws + 33554432L);
  u16* in_hi = (u16*)(ws + 50331648L);
  u16* in_lo = (u16*)(ws + 67108864L);
  u16* whT   = (u16*)(ws + 83886080L);
  u16* wlT   = (u16*)(ws + 83886080L + 1179648L);

  k_split<<<8192, 256, 0, stream>>>(inp, in_hi, in_lo, 2097152);
  k_wsplit<<<2304, 256, 0, stream>>>(convw, whT, wlT);
  k_conv<<<512, 256, 0, stream>>>(in_hi, in_lo, whT, wlT, convb, x1h, x1l);
  k_trans<<<2048, 256, 0, stream>>>(x1h, x1T);
  k_flash<<<256, 512, 0, stream>>>(x1h, x1l, x1T, inp, out);
}